// Round 1
// baseline (1103.214 us; speedup 1.0000x reference)
//
#include <hip/hip_runtime.h>
#include <stdint.h>

typedef __bf16 v8bf __attribute__((ext_vector_type(8)));
typedef float  v4f  __attribute__((ext_vector_type(4)));
typedef unsigned short u16;

#define B_ROWS 8192
#define N_SUP  100000
#define N_CLS  1000
#define DIM    768
#define CPAD   1024
#define CHUNK  25088   // 196 * 128
#define NCHUNK 4       // 4*25088 = 100352 >= 100000

// ---------- helpers ----------
__device__ __forceinline__ u16 f2bf(float f) {
    union { float f; unsigned u; } v; v.f = f;
    unsigned r = 0x7FFFu + ((v.u >> 16) & 1u);   // round-to-nearest-even
    return (u16)((v.u + r) >> 16);
}

__device__ __forceinline__ float block_sum(float v, float* red) {
    #pragma unroll
    for (int o = 32; o > 0; o >>= 1) v += __shfl_down(v, o);
    int wv = threadIdx.x >> 6, ln = threadIdx.x & 63;
    if (ln == 0) red[wv] = v;
    __syncthreads();
    return red[0] + red[1] + red[2] + red[3];
}

__device__ __forceinline__ float block_max(float v, float* red) {
    #pragma unroll
    for (int o = 32; o > 0; o >>= 1) v = fmaxf(v, __shfl_down(v, o));
    int wv = threadIdx.x >> 6, ln = threadIdx.x & 63;
    if (ln == 0) red[wv] = v;
    __syncthreads();
    return fmaxf(fmaxf(red[0], red[1]), fmaxf(red[2], red[3]));
}

// ---------- fp32 -> bf16 row conversion (one block per row, 192 thr, 4 elem/thr) ----------
__global__ void conv_rows_kernel(const float* __restrict__ in, u16* __restrict__ out) {
    size_t base = (size_t)blockIdx.x * DIM + threadIdx.x * 4;
    float4 v = *(const float4*)(in + base);
    ushort4 o;
    o.x = f2bf(v.x); o.y = f2bf(v.y); o.z = f2bf(v.z); o.w = f2bf(v.w);
    *(ushort4*)(out + base) = o;
}

// support chunk conversion with zero-pad past N_SUP
__global__ void conv_sup_kernel(const float* __restrict__ sup, u16* __restrict__ out,
                                int chunk_start) {
    int r = blockIdx.x;
    int gr = chunk_start + r;
    size_t ob = (size_t)r * DIM + threadIdx.x * 4;
    ushort4 o;
    if (gr < N_SUP) {
        float4 v = *(const float4*)(sup + (size_t)gr * DIM + threadIdx.x * 4);
        o.x = f2bf(v.x); o.y = f2bf(v.y); o.z = f2bf(v.z); o.w = f2bf(v.w);
    } else {
        o.x = 0; o.y = 0; o.z = 0; o.w = 0;
    }
    *(ushort4*)(out + ob) = o;
}

// ---------- bf16 NT GEMM: C[M,N] = A[M,K] * B[N,K]^T (+bias[col]) ----------
// grid = (N/128, M/128), block = 256. M%128==0, N%128==0, K%64==0. lda=ldb=K.
__global__ __launch_bounds__(256)
void gemm_bt_kernel(const u16* __restrict__ A, const u16* __restrict__ B,
                    float* __restrict__ C, const float* __restrict__ bias,
                    int K, int ldc) {
    __shared__ u16 As[128][64];
    __shared__ u16 Bs[128][64];

    const int tid  = threadIdx.x;
    const int wave = tid >> 6;
    const int lane = tid & 63;
    const int fq   = lane >> 4;     // quad 0..3
    const int fr   = lane & 15;
    const int blk_m = blockIdx.y * 128;
    const int blk_n = blockIdx.x * 128;
    const int wm = (wave & 1) * 64;
    const int wn = (wave >> 1) * 64;

    v4f acc[4][4];
    #pragma unroll
    for (int i = 0; i < 4; i++)
        #pragma unroll
        for (int j = 0; j < 4; j++)
            acc[i][j] = (v4f){0.f, 0.f, 0.f, 0.f};

    for (int k0 = 0; k0 < K; k0 += 64) {
        #pragma unroll
        for (int i = 0; i < 4; i++) {
            int idx = tid + i * 256;          // 1024 16B-chunks total
            int r = idx >> 3;
            int c = (idx & 7) << 3;
            *(uint4*)(&As[r][c]) = *(const uint4*)(A + (size_t)(blk_m + r) * K + k0 + c);
            *(uint4*)(&Bs[r][c]) = *(const uint4*)(B + (size_t)(blk_n + r) * K + k0 + c);
        }
        __syncthreads();
        #pragma unroll
        for (int ks = 0; ks < 2; ks++) {
            const int kk = ks * 32;
            v8bf af[4], bfr[4];
            #pragma unroll
            for (int i = 0; i < 4; i++) {
                af[i]  = *(const v8bf*)(&As[wm + i * 16 + fr][kk + fq * 8]);
                bfr[i] = *(const v8bf*)(&Bs[wn + i * 16 + fr][kk + fq * 8]);
            }
            #pragma unroll
            for (int i = 0; i < 4; i++)
                #pragma unroll
                for (int j = 0; j < 4; j++)
                    acc[i][j] = __builtin_amdgcn_mfma_f32_16x16x32_bf16(
                        af[i], bfr[j], acc[i][j], 0, 0, 0);
        }
        __syncthreads();
    }

    #pragma unroll
    for (int i = 0; i < 4; i++) {
        int row0 = blk_m + wm + i * 16 + fq * 4;
        #pragma unroll
        for (int j = 0; j < 4; j++) {
            int col = blk_n + wn + j * 16 + fr;
            float bv = bias ? bias[col] : 0.0f;
            #pragma unroll
            for (int r2 = 0; r2 < 4; r2++)
                C[(size_t)(row0 + r2) * ldc + col] = acc[i][j][r2] + bv;
        }
    }
}

// ---------- x path: silu(h)+x, l2norm; write fp32 (in place over h) + bf16 ----------
__global__ __launch_bounds__(256)
void rowwise_x_kernel(float* __restrict__ h_emb, const float* __restrict__ x,
                      u16* __restrict__ emb_bf) {
    __shared__ float red[4];
    size_t base = (size_t)blockIdx.x * DIM;
    float v[3];
    float ss = 0.f;
    #pragma unroll
    for (int i = 0; i < 3; i++) {
        int d = threadIdx.x + i * 256;
        float hv = h_emb[base + d];
        float tv = x[base + d];
        float sg = 1.0f / (1.0f + __expf(-hv));
        float val = hv * sg + tv;
        v[i] = val;
        ss += val * val;
    }
    float tot = block_sum(ss, red);
    float scale = 1.0f / fmaxf(sqrtf(tot), 1e-12f);
    #pragma unroll
    for (int i = 0; i < 3; i++) {
        int d = threadIdx.x + i * 256;
        float o = v[i] * scale;
        h_emb[base + d] = o;
        emb_bf[base + d] = f2bf(o);
    }
}

// ---------- support path: silu(h)+t, l2norm, scatter-add into sums/counts ----------
__global__ __launch_bounds__(256)
void rowwise_sup_kernel(const float* __restrict__ h, const float* __restrict__ sup,
                        const int* __restrict__ labels, float* __restrict__ sums,
                        float* __restrict__ counts, int chunk_start) {
    __shared__ float red[4];
    int r = blockIdx.x;
    int gr = chunk_start + r;
    if (gr >= N_SUP) return;
    size_t hb = (size_t)r * DIM;
    size_t sb = (size_t)gr * DIM;
    float v[3];
    float ss = 0.f;
    #pragma unroll
    for (int i = 0; i < 3; i++) {
        int d = threadIdx.x + i * 256;
        float hv = h[hb + d];
        float tv = sup[sb + d];
        float sg = 1.0f / (1.0f + __expf(-hv));
        float val = hv * sg + tv;
        v[i] = val;
        ss += val * val;
    }
    float tot = block_sum(ss, red);
    float scale = 1.0f / fmaxf(sqrtf(tot), 1e-12f);
    int lab = labels[gr];
    size_t ob = (size_t)lab * DIM;
    #pragma unroll
    for (int i = 0; i < 3; i++) {
        int d = threadIdx.x + i * 256;
        atomicAdd(&sums[ob + d], v[i] * scale);
    }
    if (threadIdx.x == 0) atomicAdd(&counts[lab], 1.0f);
}

// ---------- prototypes: mean, l2norm, zero-if-empty; bf16 out, padded to CPAD ----------
__global__ __launch_bounds__(256)
void proto_kernel(const float* __restrict__ sums, const float* __restrict__ counts,
                  u16* __restrict__ proto_bf) {
    __shared__ float red[4];
    int c = blockIdx.x;
    size_t base = (size_t)c * DIM;
    if (c >= N_CLS) {
        #pragma unroll
        for (int i = 0; i < 3; i++) proto_bf[base + threadIdx.x + i * 256] = 0;
        return;
    }
    float cnt = counts[c];
    float inv_cnt = 1.0f / fmaxf(cnt, 1.0f);
    float m[3];
    float ss = 0.f;
    #pragma unroll
    for (int i = 0; i < 3; i++) {
        int d = threadIdx.x + i * 256;
        m[i] = sums[base + d] * inv_cnt;
        ss += m[i] * m[i];
    }
    float tot = block_sum(ss, red);
    float scale = (cnt > 0.f) ? 1.0f / fmaxf(sqrtf(tot), 1e-12f) : 0.0f;
    #pragma unroll
    for (int i = 0; i < 3; i++) {
        int d = threadIdx.x + i * 256;
        proto_bf[base + d] = f2bf(m[i] * scale);
    }
}

// ---------- logits + softmax (one block per row) ----------
__global__ __launch_bounds__(256)
void softmax_kernel(const float* __restrict__ cosb, float* __restrict__ predicts,
                    float* __restrict__ logits) {
    __shared__ float redm[4];
    __shared__ float reds[4];
    int row = blockIdx.x;
    const float* crow = cosb + (size_t)row * CPAD;
    float lg[4];
    float mx = 0.0f;   // logits = exp(...) >= 0 always
    #pragma unroll
    for (int i = 0; i < 4; i++) {
        int j = threadIdx.x + i * 256;
        if (j < N_CLS) {
            float v = expf(32.0f * (crow[j] - 1.0f)) * (1.0f / 0.11f);
            lg[i] = v;
            mx = fmaxf(mx, v);
            logits[(size_t)row * N_CLS + j] = v;
        } else {
            lg[i] = -1.0f;   // sentinel (valid logits are >= 0)
        }
    }
    float mxt = block_max(mx, redm);
    float e[4];
    float s = 0.f;
    #pragma unroll
    for (int i = 0; i < 4; i++) {
        if (lg[i] >= 0.f) {
            e[i] = expf(lg[i] - mxt);
            s += e[i];
        } else e[i] = 0.f;
    }
    float st = block_sum(s, reds);
    float inv = 1.0f / st;
    #pragma unroll
    for (int i = 0; i < 4; i++) {
        int j = threadIdx.x + i * 256;
        if (j < N_CLS) predicts[(size_t)row * N_CLS + j] = e[i] * inv;
    }
}

// ---------- launch ----------
extern "C" void kernel_launch(void* const* d_in, const int* in_sizes, int n_in,
                              void* d_out, int out_size, void* d_ws, size_t ws_size,
                              hipStream_t stream) {
    const float* x      = (const float*)d_in[0];
    const float* sup    = (const float*)d_in[1];
    const int*   labels = (const int*)d_in[2];
    const float* W      = (const float*)d_in[3];
    const float* bias   = (const float*)d_in[4];

    float* out      = (float*)d_out;
    float* predicts = out;
    float* logits   = out + (size_t)B_ROWS * N_CLS;
    float* emb      = out + 2 * (size_t)B_ROWS * N_CLS;   // 8192x768 fp32

    char* ws = (char*)d_ws;
    size_t off = 0;
    u16*   w_bf     = (u16*)(ws + off); off += (size_t)DIM * DIM * 2;
    u16*   x_bf     = (u16*)(ws + off); off += (size_t)B_ROWS * DIM * 2;
    u16*   emb_bf   = (u16*)(ws + off); off += (size_t)B_ROWS * DIM * 2;
    u16*   proto_bf = (u16*)(ws + off); off += (size_t)CPAD * DIM * 2;
    float* sums     = (float*)(ws + off); off += (size_t)N_CLS * DIM * 4;
    float* counts   = (float*)(ws + off); off += (size_t)CPAD * 4;
    float* cosb     = (float*)(ws + off); off += (size_t)B_ROWS * CPAD * 4;
    u16*   sup_bf   = (u16*)(ws + off); off += (size_t)CHUNK * DIM * 2;
    float* h_chunk  = (float*)(ws + off); off += (size_t)CHUNK * DIM * 4;

    // zero segment-sum accumulators (sums and counts are contiguous)
    hipMemsetAsync(sums, 0, ((size_t)N_CLS * DIM + CPAD) * 4, stream);

    // bf16 conversions
    conv_rows_kernel<<<DIM,    192, 0, stream>>>(W, w_bf);
    conv_rows_kernel<<<B_ROWS, 192, 0, stream>>>(x, x_bf);

    // x path: h = x @ W^T + b  (h written into d_out embeddings slot, then normalized in place)
    gemm_bt_kernel<<<dim3(DIM / 128, B_ROWS / 128), 256, 0, stream>>>(
        x_bf, w_bf, emb, bias, DIM, DIM);
    rowwise_x_kernel<<<B_ROWS, 256, 0, stream>>>(emb, x, emb_bf);

    // support path, chunked
    for (int c = 0; c < NCHUNK; c++) {
        int cs = c * CHUNK;
        conv_sup_kernel<<<CHUNK, 192, 0, stream>>>(sup, sup_bf, cs);
        gemm_bt_kernel<<<dim3(DIM / 128, CHUNK / 128), 256, 0, stream>>>(
            sup_bf, w_bf, h_chunk, bias, DIM, DIM);
        rowwise_sup_kernel<<<CHUNK, 256, 0, stream>>>(h_chunk, sup, labels, sums, counts, cs);
    }

    // prototypes (padded rows 1000..1023 zeroed)
    proto_kernel<<<CPAD, 256, 0, stream>>>(sums, counts, proto_bf);

    // cos = emb @ proto^T  (padded N=1024 into ws buffer)
    gemm_bt_kernel<<<dim3(CPAD / 128, B_ROWS / 128), 256, 0, stream>>>(
        emb_bf, proto_bf, cosb, nullptr, DIM, CPAD);

    // logits + softmax
    softmax_kernel<<<B_ROWS, 256, 0, stream>>>(cosb, predicts, logits);
}

// Round 2
// 1034.810 us; speedup vs baseline: 1.0661x; 1.0661x over previous
//
#include <hip/hip_runtime.h>
#include <hip/hip_bf16.h>
#include <stdint.h>

typedef __bf16 v8bf __attribute__((ext_vector_type(8)));
typedef float  v4f  __attribute__((ext_vector_type(4)));
typedef unsigned short u16;
typedef unsigned int   u32;

#define B_ROWS   8192
#define N_SUP    100000
#define N_CLS    1000
#define DIM      768
#define CPAD     1024
#define MSUP_PAD 100352   // 784 * 128

// ---------- helpers ----------
__device__ __forceinline__ u16 f2bf(float f) {
    union { float f; u32 u; } v; v.f = f;
    u32 r = 0x7FFFu + ((v.u >> 16) & 1u);   // RNE
    return (u16)((v.u + r) >> 16);
}
__device__ __forceinline__ float bf2f(u16 b) {
    union { u32 u; float f; } v; v.u = ((u32)b) << 16; return v.f;
}
__device__ __forceinline__ u32 f2bf2(float lo, float hi) {
    __hip_bfloat162 h = __float22bfloat162_rn(make_float2(lo, hi));
    u32 u; __builtin_memcpy(&u, &h, 4); return u;
}
// async global->LDS, 16B per lane; LDS dst = wave-uniform base + lane*16
__device__ __forceinline__ void glds16(const void* g, void* l) {
    __builtin_amdgcn_global_load_lds((const __attribute__((address_space(1))) u32*)g,
                                     (__attribute__((address_space(3))) u32*)l, 16, 0, 0);
}

__device__ __forceinline__ float block_sum(float v, float* red) {
    #pragma unroll
    for (int o = 32; o > 0; o >>= 1) v += __shfl_down(v, o);
    int wv = threadIdx.x >> 6, ln = threadIdx.x & 63;
    if (ln == 0) red[wv] = v;
    __syncthreads();
    return red[0] + red[1] + red[2] + red[3];
}
__device__ __forceinline__ float block_max(float v, float* red) {
    #pragma unroll
    for (int o = 32; o > 0; o >>= 1) v = fmaxf(v, __shfl_down(v, o));
    int wv = threadIdx.x >> 6, ln = threadIdx.x & 63;
    if (ln == 0) red[wv] = v;
    __syncthreads();
    return fmaxf(fmaxf(red[0], red[1]), fmaxf(red[2], red[3]));
}

// ---------- W fp32 -> bf16 (768 blocks x 192 thr, 4 elem/thr) ----------
__global__ void conv_w_kernel(const float* __restrict__ in, u16* __restrict__ out) {
    size_t base = (size_t)blockIdx.x * DIM + threadIdx.x * 4;
    float4 v = *(const float4*)(in + base);
    ushort4 o;
    o.x = f2bf(v.x); o.y = f2bf(v.y); o.z = f2bf(v.z); o.w = f2bf(v.w);
    *(ushort4*)(out + base) = o;
}

// ---------- adapter GEMM: h = A @ W^T + b; epilogue val = silu(h)+A, row ss ----------
// A fp32 [M,768] (converted to bf16 inline during staging), W_bf [768,768] bf16.
// grid = (6, M/128), block = 256.
template<bool BF16OUT>
__global__ __launch_bounds__(256)
void adapter_gemm_kernel(const float* __restrict__ A, const u16* __restrict__ Wb,
                         const float* __restrict__ bias,
                         u16* __restrict__ out_bf, float* __restrict__ out_f,
                         float* __restrict__ ss, int Mreal) {
    __shared__ u16 As[128 * 64];
    __shared__ u16 Bs[128 * 64];

    const int tid  = threadIdx.x;
    const int wave = tid >> 6, lane = tid & 63;
    const int fq = lane >> 4, fr = lane & 15;
    const int blk_m = blockIdx.y * 128, blk_n = blockIdx.x * 128;
    const int wm = (wave & 1) * 64, wn = (wave >> 1) * 64;

    v4f acc[4][4];
    #pragma unroll
    for (int i = 0; i < 4; i++)
        #pragma unroll
        for (int j = 0; j < 4; j++) acc[i][j] = (v4f){0.f, 0.f, 0.f, 0.f};

    // B (W) staging via global_load_lds: per pass p, this wave fills 1KB at
    // Bs + p*2048 + wave*512 (u16 elems); lane covers 16B at +lane*16.
    const int rb = lane >> 3;           // 0..7 rows within wave's 8-row strip
    const int cb = (lane & 7) * 8;      // col elems
    const u16* gB = Wb + (size_t)(blk_n + wave * 8 + rb) * DIM + cb;

    for (int k0 = 0; k0 < DIM; k0 += 64) {
        #pragma unroll
        for (int p = 0; p < 4; p++)
            glds16(gB + (size_t)p * 32 * DIM + k0, Bs + p * 2048 + wave * 512);
        // A staging: load fp32, convert, ds_write (overlaps B DMA)
        #pragma unroll
        for (int p = 0; p < 8; p++) {
            int idx = tid + p * 256;
            int row = idx >> 4;
            int c4  = (idx & 15) << 2;
            int gr  = blk_m + row; if (gr >= Mreal) gr = Mreal - 1;
            float4 v = *(const float4*)(A + (size_t)gr * DIM + k0 + c4);
            *(uint2*)(As + row * 64 + c4) = make_uint2(f2bf2(v.x, v.y), f2bf2(v.z, v.w));
        }
        __syncthreads();
        #pragma unroll
        for (int ks = 0; ks < 2; ks++) {
            const int kk = ks * 32;
            v8bf af[4], bfr[4];
            #pragma unroll
            for (int i = 0; i < 4; i++) {
                af[i]  = *(const v8bf*)(As + (wm + i * 16 + fr) * 64 + kk + fq * 8);
                bfr[i] = *(const v8bf*)(Bs + (wn + i * 16 + fr) * 64 + kk + fq * 8);
            }
            #pragma unroll
            for (int i = 0; i < 4; i++)
                #pragma unroll
                for (int j = 0; j < 4; j++)
                    acc[i][j] = __builtin_amdgcn_mfma_f32_16x16x32_bf16(
                        af[i], bfr[j], acc[i][j], 0, 0, 0);
        }
        __syncthreads();
    }

    // epilogue: val = silu(h) + t; write val; reduce val^2 per row -> ss
    #pragma unroll
    for (int i = 0; i < 4; i++) {
        int r0 = blk_m + wm + i * 16 + fq * 4;
        float ssp[4] = {0.f, 0.f, 0.f, 0.f};
        #pragma unroll
        for (int j = 0; j < 4; j++) {
            int col = blk_n + wn + j * 16 + fr;
            float bv = bias[col];
            #pragma unroll
            for (int r2 = 0; r2 < 4; r2++) {
                int gr = r0 + r2;
                bool ok = gr < Mreal;
                float h = acc[i][j][r2] + bv;
                float t = ok ? A[(size_t)gr * DIM + col] : 0.f;
                float v = h / (1.f + __expf(-h)) + t;
                ssp[r2] += v * v;
                if (ok) {
                    if (BF16OUT) out_bf[(size_t)gr * DIM + col] = f2bf(v);
                    else         out_f[(size_t)gr * DIM + col] = v;
                }
            }
        }
        #pragma unroll
        for (int r2 = 0; r2 < 4; r2++) {
            float s = ssp[r2];
            s += __shfl_xor(s, 1); s += __shfl_xor(s, 2);
            s += __shfl_xor(s, 4); s += __shfl_xor(s, 8);
            int gr = r0 + r2;
            if (fr == 0 && gr < Mreal) atomicAdd(&ss[gr], s);
        }
    }
}

// ---------- x normalize: emb = val / max(||val||, eps); fp32 + bf16 out ----------
__global__ void norm_x_kernel(const float* __restrict__ val, const float* __restrict__ ss,
                              float* __restrict__ emb, u16* __restrict__ emb_bf) {
    int row = blockIdx.x;
    float sc = 1.f / fmaxf(sqrtf(ss[row]), 1e-12f);
    size_t b = (size_t)row * DIM + threadIdx.x * 4;
    float4 v = *(const float4*)(val + b);
    float4 o; o.x = v.x * sc; o.y = v.y * sc; o.z = v.z * sc; o.w = v.w * sc;
    *(float4*)(emb + b) = o;
    ushort4 ob; ob.x = f2bf(o.x); ob.y = f2bf(o.y); ob.z = f2bf(o.z); ob.w = f2bf(o.w);
    *(ushort4*)(emb_bf + b) = ob;
}

// ---------- prototypes: one class per block; queue-gather, mean, l2norm ----------
__global__ __launch_bounds__(256)
void proto_kernel(const u16* __restrict__ val_bf, const float* __restrict__ ss,
                  const int* __restrict__ labels, u16* __restrict__ proto_bf) {
    __shared__ int queue[256];
    __shared__ int qn;
    __shared__ float red[4];
    const int cls = blockIdx.x, tid = threadIdx.x;
    if (tid == 0) qn = 0;
    __syncthreads();
    // scan labels (int4 vectorized; N_SUP % 4 == 0)
    for (int i4 = tid; i4 < N_SUP / 4; i4 += 256) {
        int4 L = *(const int4*)(labels + i4 * 4);
        if (L.x == cls) queue[atomicAdd(&qn, 1) & 255] = i4 * 4;
        if (L.y == cls) queue[atomicAdd(&qn, 1) & 255] = i4 * 4 + 1;
        if (L.z == cls) queue[atomicAdd(&qn, 1) & 255] = i4 * 4 + 2;
        if (L.w == cls) queue[atomicAdd(&qn, 1) & 255] = i4 * 4 + 3;
    }
    __syncthreads();
    const int n = qn < 256 ? qn : 256;   // ~100 expected, sigma ~10: cap unreachable
    float a0 = 0.f, a1 = 0.f, a2 = 0.f;
    for (int e = 0; e < n; e++) {
        int row = queue[e];
        float sc = 1.f / fmaxf(sqrtf(ss[row]), 1e-12f);
        const u16* vr = val_bf + (size_t)row * DIM;
        a0 += bf2f(vr[tid])       * sc;
        a1 += bf2f(vr[tid + 256]) * sc;
        a2 += bf2f(vr[tid + 512]) * sc;
    }
    float inv_cnt = 1.f / fmaxf((float)n, 1.f);
    float m0 = a0 * inv_cnt, m1 = a1 * inv_cnt, m2 = a2 * inv_cnt;
    float tot = block_sum(m0 * m0 + m1 * m1 + m2 * m2, red);
    float sc2 = (n > 0) ? 1.f / fmaxf(sqrtf(tot), 1e-12f) : 0.f;
    size_t b = (size_t)cls * DIM;
    proto_bf[b + tid]       = f2bf(m0 * sc2);
    proto_bf[b + tid + 256] = f2bf(m1 * sc2);
    proto_bf[b + tid + 512] = f2bf(m2 * sc2);
}

// ---------- cos GEMM (bf16 x bf16, glds both) with fused exp -> logits ----------
// grid = (CPAD/128, B_ROWS/128)
__global__ __launch_bounds__(256)
void cos_gemm_kernel(const u16* __restrict__ Ab, const u16* __restrict__ Pb,
                     float* __restrict__ logits) {
    __shared__ u16 As[128 * 64];
    __shared__ u16 Bs[128 * 64];
    const int tid  = threadIdx.x;
    const int wave = tid >> 6, lane = tid & 63;
    const int fq = lane >> 4, fr = lane & 15;
    const int blk_m = blockIdx.y * 128, blk_n = blockIdx.x * 128;
    const int wm = (wave & 1) * 64, wn = (wave >> 1) * 64;

    v4f acc[4][4];
    #pragma unroll
    for (int i = 0; i < 4; i++)
        #pragma unroll
        for (int j = 0; j < 4; j++) acc[i][j] = (v4f){0.f, 0.f, 0.f, 0.f};

    const int rb = lane >> 3;
    const int cb = (lane & 7) * 8;
    const u16* gA = Ab + (size_t)(blk_m + wave * 8 + rb) * DIM + cb;
    const u16* gB = Pb + (size_t)(blk_n + wave * 8 + rb) * DIM + cb;

    for (int k0 = 0; k0 < DIM; k0 += 64) {
        #pragma unroll
        for (int p = 0; p < 4; p++) {
            glds16(gA + (size_t)p * 32 * DIM + k0, As + p * 2048 + wave * 512);
            glds16(gB + (size_t)p * 32 * DIM + k0, Bs + p * 2048 + wave * 512);
        }
        __syncthreads();
        #pragma unroll
        for (int ks = 0; ks < 2; ks++) {
            const int kk = ks * 32;
            v8bf af[4], bfr[4];
            #pragma unroll
            for (int i = 0; i < 4; i++) {
                af[i]  = *(const v8bf*)(As + (wm + i * 16 + fr) * 64 + kk + fq * 8);
                bfr[i] = *(const v8bf*)(Bs + (wn + i * 16 + fr) * 64 + kk + fq * 8);
            }
            #pragma unroll
            for (int i = 0; i < 4; i++)
                #pragma unroll
                for (int j = 0; j < 4; j++)
                    acc[i][j] = __builtin_amdgcn_mfma_f32_16x16x32_bf16(
                        af[i], bfr[j], acc[i][j], 0, 0, 0);
        }
        __syncthreads();
    }

    #pragma unroll
    for (int i = 0; i < 4; i++) {
        int r0 = blk_m + wm + i * 16 + fq * 4;
        #pragma unroll
        for (int j = 0; j < 4; j++) {
            int col = blk_n + wn + j * 16 + fr;
            if (col < N_CLS) {
                #pragma unroll
                for (int r2 = 0; r2 < 4; r2++) {
                    float c = acc[i][j][r2];
                    logits[(size_t)(r0 + r2) * N_CLS + col] =
                        expf(32.0f * (c - 1.0f)) * (1.0f / 0.11f);
                }
            }
        }
    }
}

// ---------- softmax over logits rows ----------
__global__ __launch_bounds__(256)
void softmax_kernel(const float* __restrict__ logits, float* __restrict__ predicts) {
    __shared__ float redm[4];
    __shared__ float reds[4];
    int row = blockIdx.x, tid = threadIdx.x;
    const float* lr = logits + (size_t)row * N_CLS;
    float4 lg = make_float4(-1.f, -1.f, -1.f, -1.f);
    bool act = tid < N_CLS / 4;   // 250
    if (act) lg = *(const float4*)(lr + tid * 4);
    float mx = fmaxf(fmaxf(lg.x, lg.y), fmaxf(lg.z, lg.w));  // logits >= 0
    float mxt = block_max(mx, redm);
    float4 e = make_float4(0.f, 0.f, 0.f, 0.f);
    float s = 0.f;
    if (act) {
        e.x = expf(lg.x - mxt); e.y = expf(lg.y - mxt);
        e.z = expf(lg.z - mxt); e.w = expf(lg.w - mxt);
        s = e.x + e.y + e.z + e.w;
    }
    float st = block_sum(s, reds);
    float inv = 1.f / st;
    if (act) {
        float4 o; o.x = e.x * inv; o.y = e.y * inv; o.z = e.z * inv; o.w = e.w * inv;
        *(float4*)(predicts + (size_t)row * N_CLS + tid * 4) = o;
    }
}

// ---------- launch ----------
extern "C" void kernel_launch(void* const* d_in, const int* in_sizes, int n_in,
                              void* d_out, int out_size, void* d_ws, size_t ws_size,
                              hipStream_t stream) {
    const float* x      = (const float*)d_in[0];
    const float* sup    = (const float*)d_in[1];
    const int*   labels = (const int*)d_in[2];
    const float* W      = (const float*)d_in[3];
    const float* bias   = (const float*)d_in[4];

    float* predicts = (float*)d_out;
    float* logits   = predicts + (size_t)B_ROWS * N_CLS;
    float* emb      = logits + (size_t)B_ROWS * N_CLS;   // 8192x768 fp32

    char* ws = (char*)d_ws;
    size_t off = 0;
    u16*   w_bf     = (u16*)(ws + off);   off += (size_t)DIM * DIM * 2;
    u16*   val_sup  = (u16*)(ws + off);   off += (size_t)MSUP_PAD * DIM * 2;
    float* val_x    = (float*)(ws + off); off += (size_t)B_ROWS * DIM * 4;
    u16*   emb_bf   = (u16*)(ws + off);   off += (size_t)B_ROWS * DIM * 2;
    u16*   proto_bf = (u16*)(ws + off);   off += (size_t)CPAD * DIM * 2;
    float* ss_sup   = (float*)(ws + off); off += (size_t)MSUP_PAD * 4;
    float* ss_x     = (float*)(ws + off); off += (size_t)B_ROWS * 4;

    // zero row-sum-of-squares accumulators (ss_sup and ss_x contiguous)
    hipMemsetAsync(ss_sup, 0, ((size_t)MSUP_PAD + B_ROWS) * 4, stream);

    conv_w_kernel<<<DIM, 192, 0, stream>>>(W, w_bf);

    // x path
    adapter_gemm_kernel<false><<<dim3(DIM / 128, B_ROWS / 128), 256, 0, stream>>>(
        x, w_bf, bias, nullptr, val_x, ss_x, B_ROWS);
    norm_x_kernel<<<B_ROWS, 192, 0, stream>>>(val_x, ss_x, emb, emb_bf);

    // support path
    adapter_gemm_kernel<true><<<dim3(DIM / 128, MSUP_PAD / 128), 256, 0, stream>>>(
        sup, w_bf, bias, val_sup, nullptr, ss_sup, N_SUP);
    proto_kernel<<<CPAD, 256, 0, stream>>>(val_sup, ss_sup, labels, proto_bf);

    // cos + exp -> logits (d_out), then softmax -> predicts (d_out)
    cos_gemm_kernel<<<dim3(CPAD / 128, B_ROWS / 128), 256, 0, stream>>>(
        emb_bf, proto_bf, logits);
    softmax_kernel<<<B_ROWS, 256, 0, stream>>>(logits, predicts);
}

// Round 3
// 915.175 us; speedup vs baseline: 1.2055x; 1.1307x over previous
//
#include <hip/hip_runtime.h>
#include <hip/hip_bf16.h>
#include <stdint.h>

typedef __bf16 v8bf __attribute__((ext_vector_type(8)));
typedef float  v4f  __attribute__((ext_vector_type(4)));
typedef unsigned short u16;
typedef unsigned int   u32;

#define B_ROWS   8192
#define N_SUP    100000
#define N_CLS    1000
#define DIM      768
#define CPAD     1024
#define MSUP_PAD 100352   // 784 * 128

// ---------- helpers ----------
__device__ __forceinline__ u16 f2bf(float f) {
    union { float f; u32 u; } v; v.f = f;
    u32 r = 0x7FFFu + ((v.u >> 16) & 1u);   // RNE
    return (u16)((v.u + r) >> 16);
}
__device__ __forceinline__ float bf2f(u16 b) {
    union { u32 u; float f; } v; v.u = ((u32)b) << 16; return v.f;
}
// async global->LDS, 16B per lane; LDS dst = wave-uniform base + lane*16
__device__ __forceinline__ void glds16(const void* g, void* l) {
    __builtin_amdgcn_global_load_lds((const __attribute__((address_space(1))) u32*)g,
                                     (__attribute__((address_space(3))) u32*)l, 16, 0, 0);
}

__device__ __forceinline__ float block_sum(float v, float* red) {
    #pragma unroll
    for (int o = 32; o > 0; o >>= 1) v += __shfl_down(v, o);
    int wv = threadIdx.x >> 6, ln = threadIdx.x & 63;
    if (ln == 0) red[wv] = v;
    __syncthreads();
    return red[0] + red[1] + red[2] + red[3];
}
__device__ __forceinline__ float block_max(float v, float* red) {
    #pragma unroll
    for (int o = 32; o > 0; o >>= 1) v = fmaxf(v, __shfl_down(v, o));
    int wv = threadIdx.x >> 6, ln = threadIdx.x & 63;
    if (ln == 0) red[wv] = v;
    __syncthreads();
    return fmaxf(fmaxf(red[0], red[1]), fmaxf(red[2], red[3]));
}

// ---------- fp32 -> bf16 row conversion, zero-pad rows >= n_real ----------
// one block per row, 192 thr, 4 elem/thr
__global__ void conv_pad_kernel(const float* __restrict__ in, u16* __restrict__ out,
                                int n_real) {
    int r = blockIdx.x;
    size_t ob = (size_t)r * DIM + threadIdx.x * 4;
    ushort4 o;
    if (r < n_real) {
        float4 v = *(const float4*)(in + ob);
        o.x = f2bf(v.x); o.y = f2bf(v.y); o.z = f2bf(v.z); o.w = f2bf(v.w);
    } else {
        o.x = 0; o.y = 0; o.z = 0; o.w = 0;
    }
    *(ushort4*)(out + ob) = o;
}

// ---------- adapter GEMM: h = A @ W^T + b; epilogue val = silu(h)+t, row ss ----------
// A bf16 [M,768] (M % 128 == 0, padded rows zero), Wb bf16 [768,768].
// t re-read from A (bf16). grid = (6, M/128), block = 256. m97-style glds staging.
__global__ __launch_bounds__(256)
void adapter_gemm_kernel(const u16* __restrict__ A, const u16* __restrict__ Wb,
                         const float* __restrict__ bias,
                         u16* __restrict__ val, float* __restrict__ ss) {
    __shared__ u16 As[128 * 64];
    __shared__ u16 Bs[128 * 64];

    const int tid  = threadIdx.x;
    const int wave = tid >> 6, lane = tid & 63;
    const int fq = lane >> 4, fr = lane & 15;
    const int blk_m = blockIdx.y * 128, blk_n = blockIdx.x * 128;
    const int wm = (wave & 1) * 64, wn = (wave >> 1) * 64;

    v4f acc[4][4];
    #pragma unroll
    for (int i = 0; i < 4; i++)
        #pragma unroll
        for (int j = 0; j < 4; j++) acc[i][j] = (v4f){0.f, 0.f, 0.f, 0.f};

    const int rb = lane >> 3;           // 0..7 rows within a wave's 8-row strip
    const int cb = (lane & 7) * 8;      // col elems (16B)
    const u16* gA = A  + (size_t)(blk_m + wave * 8 + rb) * DIM + cb;
    const u16* gB = Wb + (size_t)(blk_n + wave * 8 + rb) * DIM + cb;

    for (int k0 = 0; k0 < DIM; k0 += 64) {
        #pragma unroll
        for (int p = 0; p < 4; p++) {
            glds16(gA + (size_t)p * 32 * DIM + k0, As + p * 2048 + wave * 512);
            glds16(gB + (size_t)p * 32 * DIM + k0, Bs + p * 2048 + wave * 512);
        }
        __syncthreads();
        #pragma unroll
        for (int ks = 0; ks < 2; ks++) {
            const int kk = ks * 32;
            v8bf af[4], bfr[4];
            #pragma unroll
            for (int i = 0; i < 4; i++) {
                af[i]  = *(const v8bf*)(As + (wm + i * 16 + fr) * 64 + kk + fq * 8);
                bfr[i] = *(const v8bf*)(Bs + (wn + i * 16 + fr) * 64 + kk + fq * 8);
            }
            #pragma unroll
            for (int i = 0; i < 4; i++)
                #pragma unroll
                for (int j = 0; j < 4; j++)
                    acc[i][j] = __builtin_amdgcn_mfma_f32_16x16x32_bf16(
                        af[i], bfr[j], acc[i][j], 0, 0, 0);
        }
        __syncthreads();
    }

    // epilogue: val = silu(h) + t (t from bf16 A); write val bf16; row ss -> atomic
    #pragma unroll
    for (int i = 0; i < 4; i++) {
        int r0 = blk_m + wm + i * 16 + fq * 4;
        float ssp[4] = {0.f, 0.f, 0.f, 0.f};
        #pragma unroll
        for (int j = 0; j < 4; j++) {
            int col = blk_n + wn + j * 16 + fr;
            float bv = bias[col];
            #pragma unroll
            for (int r2 = 0; r2 < 4; r2++) {
                int gr = r0 + r2;
                float h = acc[i][j][r2] + bv;
                float t = bf2f(A[(size_t)gr * DIM + col]);
                float v = h / (1.f + __expf(-h)) + t;
                ssp[r2] += v * v;
                val[(size_t)gr * DIM + col] = f2bf(v);
            }
        }
        #pragma unroll
        for (int r2 = 0; r2 < 4; r2++) {
            float s = ssp[r2];
            s += __shfl_xor(s, 1); s += __shfl_xor(s, 2);
            s += __shfl_xor(s, 4); s += __shfl_xor(s, 8);
            if (fr == 0) atomicAdd(&ss[r0 + r2], s);
        }
    }
}

// ---------- x normalize: emb = val / max(||val||, eps); fp32 + bf16 out ----------
__global__ void norm_x_kernel(const u16* __restrict__ val, const float* __restrict__ ss,
                              float* __restrict__ emb, u16* __restrict__ emb_bf) {
    int row = blockIdx.x;
    float sc = 1.f / fmaxf(sqrtf(ss[row]), 1e-12f);
    size_t b = (size_t)row * DIM + threadIdx.x * 4;
    ushort4 v = *(const ushort4*)(val + b);
    float4 o;
    o.x = bf2f(v.x) * sc; o.y = bf2f(v.y) * sc;
    o.z = bf2f(v.z) * sc; o.w = bf2f(v.w) * sc;
    *(float4*)(emb + b) = o;
    ushort4 ob; ob.x = f2bf(o.x); ob.y = f2bf(o.y); ob.z = f2bf(o.z); ob.w = f2bf(o.w);
    *(ushort4*)(emb_bf + b) = ob;
}

// ---------- prototypes: one class per block; queue-gather, mean, l2norm ----------
__global__ __launch_bounds__(256)
void proto_kernel(const u16* __restrict__ val_bf, const float* __restrict__ ss,
                  const int* __restrict__ labels, u16* __restrict__ proto_bf) {
    __shared__ int queue[256];
    __shared__ int qn;
    __shared__ float red[4];
    const int cls = blockIdx.x, tid = threadIdx.x;
    if (tid == 0) qn = 0;
    __syncthreads();
    for (int i4 = tid; i4 < N_SUP / 4; i4 += 256) {
        int4 L = *(const int4*)(labels + i4 * 4);
        if (L.x == cls) queue[atomicAdd(&qn, 1) & 255] = i4 * 4;
        if (L.y == cls) queue[atomicAdd(&qn, 1) & 255] = i4 * 4 + 1;
        if (L.z == cls) queue[atomicAdd(&qn, 1) & 255] = i4 * 4 + 2;
        if (L.w == cls) queue[atomicAdd(&qn, 1) & 255] = i4 * 4 + 3;
    }
    __syncthreads();
    const int n = qn < 256 ? qn : 256;   // ~100 expected; cap unreachable
    float a0 = 0.f, a1 = 0.f, a2 = 0.f;
    for (int e = 0; e < n; e++) {
        int row = queue[e];
        float sc = 1.f / fmaxf(sqrtf(ss[row]), 1e-12f);
        const u16* vr = val_bf + (size_t)row * DIM;
        a0 += bf2f(vr[tid])       * sc;
        a1 += bf2f(vr[tid + 256]) * sc;
        a2 += bf2f(vr[tid + 512]) * sc;
    }
    float inv_cnt = 1.f / fmaxf((float)n, 1.f);
    float m0 = a0 * inv_cnt, m1 = a1 * inv_cnt, m2 = a2 * inv_cnt;
    float tot = block_sum(m0 * m0 + m1 * m1 + m2 * m2, red);
    float sc2 = (n > 0) ? 1.f / fmaxf(sqrtf(tot), 1e-12f) : 0.f;
    size_t b = (size_t)cls * DIM;
    proto_bf[b + tid]       = f2bf(m0 * sc2);
    proto_bf[b + tid + 256] = f2bf(m1 * sc2);
    proto_bf[b + tid + 512] = f2bf(m2 * sc2);
}

// ---------- cos GEMM (bf16 x bf16, glds both) with fused exp -> logits ----------
// grid = (CPAD/128, B_ROWS/128)
__global__ __launch_bounds__(256)
void cos_gemm_kernel(const u16* __restrict__ Ab, const u16* __restrict__ Pb,
                     float* __restrict__ logits) {
    __shared__ u16 As[128 * 64];
    __shared__ u16 Bs[128 * 64];
    const int tid  = threadIdx.x;
    const int wave = tid >> 6, lane = tid & 63;
    const int fq = lane >> 4, fr = lane & 15;
    const int blk_m = blockIdx.y * 128, blk_n = blockIdx.x * 128;
    const int wm = (wave & 1) * 64, wn = (wave >> 1) * 64;

    v4f acc[4][4];
    #pragma unroll
    for (int i = 0; i < 4; i++)
        #pragma unroll
        for (int j = 0; j < 4; j++) acc[i][j] = (v4f){0.f, 0.f, 0.f, 0.f};

    const int rb = lane >> 3;
    const int cb = (lane & 7) * 8;
    const u16* gA = Ab + (size_t)(blk_m + wave * 8 + rb) * DIM + cb;
    const u16* gB = Pb + (size_t)(blk_n + wave * 8 + rb) * DIM + cb;

    for (int k0 = 0; k0 < DIM; k0 += 64) {
        #pragma unroll
        for (int p = 0; p < 4; p++) {
            glds16(gA + (size_t)p * 32 * DIM + k0, As + p * 2048 + wave * 512);
            glds16(gB + (size_t)p * 32 * DIM + k0, Bs + p * 2048 + wave * 512);
        }
        __syncthreads();
        #pragma unroll
        for (int ks = 0; ks < 2; ks++) {
            const int kk = ks * 32;
            v8bf af[4], bfr[4];
            #pragma unroll
            for (int i = 0; i < 4; i++) {
                af[i]  = *(const v8bf*)(As + (wm + i * 16 + fr) * 64 + kk + fq * 8);
                bfr[i] = *(const v8bf*)(Bs + (wn + i * 16 + fr) * 64 + kk + fq * 8);
            }
            #pragma unroll
            for (int i = 0; i < 4; i++)
                #pragma unroll
                for (int j = 0; j < 4; j++)
                    acc[i][j] = __builtin_amdgcn_mfma_f32_16x16x32_bf16(
                        af[i], bfr[j], acc[i][j], 0, 0, 0);
        }
        __syncthreads();
    }

    #pragma unroll
    for (int i = 0; i < 4; i++) {
        int r0 = blk_m + wm + i * 16 + fq * 4;
        #pragma unroll
        for (int j = 0; j < 4; j++) {
            int col = blk_n + wn + j * 16 + fr;
            if (col < N_CLS) {
                #pragma unroll
                for (int r2 = 0; r2 < 4; r2++) {
                    float c = acc[i][j][r2];
                    logits[(size_t)(r0 + r2) * N_CLS + col] =
                        __expf(32.0f * (c - 1.0f)) * (1.0f / 0.11f);
                }
            }
        }
    }
}

// ---------- softmax over logits rows ----------
__global__ __launch_bounds__(256)
void softmax_kernel(const float* __restrict__ logits, float* __restrict__ predicts) {
    __shared__ float redm[4];
    __shared__ float reds[4];
    int row = blockIdx.x, tid = threadIdx.x;
    const float* lr = logits + (size_t)row * N_CLS;
    float4 lg = make_float4(-1.f, -1.f, -1.f, -1.f);
    bool act = tid < N_CLS / 4;   // 250
    if (act) lg = *(const float4*)(lr + tid * 4);
    float mx = fmaxf(fmaxf(lg.x, lg.y), fmaxf(lg.z, lg.w));  // logits >= 0
    float mxt = block_max(mx, redm);
    float4 e = make_float4(0.f, 0.f, 0.f, 0.f);
    float s = 0.f;
    if (act) {
        e.x = __expf(lg.x - mxt); e.y = __expf(lg.y - mxt);
        e.z = __expf(lg.z - mxt); e.w = __expf(lg.w - mxt);
        s = e.x + e.y + e.z + e.w;
    }
    float st = block_sum(s, reds);
    float inv = 1.f / st;
    if (act) {
        float4 o; o.x = e.x * inv; o.y = e.y * inv; o.z = e.z * inv; o.w = e.w * inv;
        *(float4*)(predicts + (size_t)row * N_CLS + tid * 4) = o;
    }
}

// ---------- launch ----------
extern "C" void kernel_launch(void* const* d_in, const int* in_sizes, int n_in,
                              void* d_out, int out_size, void* d_ws, size_t ws_size,
                              hipStream_t stream) {
    const float* x      = (const float*)d_in[0];
    const float* sup    = (const float*)d_in[1];
    const int*   labels = (const int*)d_in[2];
    const float* W      = (const float*)d_in[3];
    const float* bias   = (const float*)d_in[4];

    float* predicts = (float*)d_out;
    float* logits   = predicts + (size_t)B_ROWS * N_CLS;
    float* emb      = logits + (size_t)B_ROWS * N_CLS;   // 8192x768 fp32

    char* ws = (char*)d_ws;
    size_t off = 0;
    u16*   w_bf     = (u16*)(ws + off);   off += (size_t)DIM * DIM * 2;
    u16*   x_bf     = (u16*)(ws + off);   off += (size_t)B_ROWS * DIM * 2;
    u16*   sup_bf   = (u16*)(ws + off);   off += (size_t)MSUP_PAD * DIM * 2;
    u16*   val_x    = (u16*)(ws + off);   off += (size_t)B_ROWS * DIM * 2;
    u16*   val_sup  = (u16*)(ws + off);   off += (size_t)MSUP_PAD * DIM * 2;
    u16*   emb_bf   = (u16*)(ws + off);   off += (size_t)B_ROWS * DIM * 2;
    u16*   proto_bf = (u16*)(ws + off);   off += (size_t)CPAD * DIM * 2;
    float* ss_sup   = (float*)(ws + off); off += (size_t)MSUP_PAD * 4;
    float* ss_x     = (float*)(ws + off); off += (size_t)B_ROWS * 4;

    // zero row-sum-of-squares accumulators (contiguous)
    hipMemsetAsync(ss_sup, 0, ((size_t)MSUP_PAD + B_ROWS) * 4, stream);

    // bf16 conversions (streaming, guard-free GEMM afterwards)
    conv_pad_kernel<<<DIM,      192, 0, stream>>>(W,   w_bf,   DIM);
    conv_pad_kernel<<<B_ROWS,   192, 0, stream>>>(x,   x_bf,   B_ROWS);
    conv_pad_kernel<<<MSUP_PAD, 192, 0, stream>>>(sup, sup_bf, N_SUP);

    // adapter GEMMs (val = silu(A@W^T+b)+A, bf16; per-row ss)
    adapter_gemm_kernel<<<dim3(DIM / 128, B_ROWS / 128), 256, 0, stream>>>(
        x_bf, w_bf, bias, val_x, ss_x);
    adapter_gemm_kernel<<<dim3(DIM / 128, MSUP_PAD / 128), 256, 0, stream>>>(
        sup_bf, w_bf, bias, val_sup, ss_sup);

    // x normalize -> emb (fp32, d_out) + emb_bf
    norm_x_kernel<<<B_ROWS, 192, 0, stream>>>(val_x, ss_x, emb, emb_bf);

    // prototypes (rows >= N_CLS get zeros via n==0 path)
    proto_kernel<<<CPAD, 256, 0, stream>>>(val_sup, ss_sup, labels, proto_bf);

    // cos + exp -> logits (d_out), then softmax -> predicts (d_out)
    cos_gemm_kernel<<<dim3(CPAD / 128, B_ROWS / 128), 256, 0, stream>>>(
        emb_bf, proto_bf, logits);
    softmax_kernel<<<B_ROWS, 256, 0, stream>>>(logits, predicts);
}